// Round 1
// 633.523 us; speedup vs baseline: 1.0544x; 1.0544x over previous
//
#include <hip/hip_runtime.h>
#include <math.h>

// Problem constants (from reference)
#define C    81
#define REG  405    // C*5
#define OUTW 486    // C + C*5
#define RPB  8      // rows per 256-thread block (8*81, 8*405, 8*486 floats are all 16B-multiples)

// LDS layout (floats)
#define S_LOG  (RPB * C)      // 648
#define S_REG  (RPB * REG)    // 3240
#define S_PROP (RPB * 5)      // 40
#define S_IN   (S_LOG + S_REG + S_PROP)   // 3928
#define S_OUT  (RPB * OUTW)   // 3888

__device__ __forceinline__ float wave_max(float v) {
    #pragma unroll
    for (int off = 32; off > 0; off >>= 1)
        v = fmaxf(v, __shfl_xor(v, off));
    return v;
}
__device__ __forceinline__ float wave_sum(float v) {
    #pragma unroll
    for (int off = 32; off > 0; off >>= 1)
        v += __shfl_xor(v, off);
    return v;
}

__global__ __launch_bounds__(256) void postproc_kernel(
    const float* __restrict__ logits,
    const float* __restrict__ regr,
    const float* __restrict__ prop,
    float* __restrict__ out,
    int n_rows)
{
    __shared__ float s_in[S_IN];
    __shared__ float s_out[S_OUT];

    const int tid  = threadIdx.x;
    const int lane = tid & 63;
    const int wid  = tid >> 6;          // 0..3
    const int row0 = blockIdx.x * RPB;
    const int nrh  = min(RPB, n_rows - row0);
    if (nrh <= 0) return;

    float* s_log  = s_in;
    float* s_reg  = s_in + S_LOG;
    float* s_prop = s_in + S_LOG + S_REG;

    // ---------------- stage in (float4, fully coalesced & aligned) ----------------
    if (nrh == RPB) {
        const float4* gl = (const float4*)(logits + (size_t)row0 * C);   // 2592B-mult base
        const float4* gr = (const float4*)(regr   + (size_t)row0 * REG); // 12960B-mult base
        float4* sl = (float4*)s_log;
        float4* sr = (float4*)s_reg;
        #pragma unroll
        for (int t = tid; t < S_LOG / 4; t += 256) sl[t] = gl[t];   // 162 vec4
        #pragma unroll
        for (int t = tid; t < S_REG / 4; t += 256) sr[t] = gr[t];   // 810 vec4
        if (tid < S_PROP) s_prop[tid] = prop[(size_t)row0 * 5 + tid];
    } else {
        // rare tail block: scalar staging with guards
        for (int t = tid; t < nrh * C;   t += 256) s_log[t]  = logits[(size_t)row0 * C + t];
        for (int t = tid; t < nrh * REG; t += 256) s_reg[t]  = regr[(size_t)row0 * REG + t];
        for (int t = tid; t < nrh * 5;   t += 256) s_prop[t] = prop[(size_t)row0 * 5 + t];
    }
    __syncthreads();

    // ---------------- compute: one wave handles 2 rows ----------------
    const float BBOX_CLIP = 4.135166556742356f;   // log(1000/16)
    const float RAD2DEG   = 57.29577951308232f;   // 180/pi

    #pragma unroll
    for (int rr = 0; rr < 2; ++rr) {
        const int r = wid * 2 + rr;
        if (r < nrh) {
            // ---- softmax over 81 logits (LDS reads, lane-consecutive: conflict-free) ----
            const float* lg = s_log + r * C;
            float x0 = lg[lane];
            float x1 = (lane < C - 64) ? lg[64 + lane] : -INFINITY;
            float m  = wave_max(fmaxf(x0, x1));
            float e0 = __expf(x0 - m);
            float e1 = (lane < C - 64) ? __expf(x1 - m) : 0.0f;
            float inv = 1.0f / wave_sum(e0 + e1);

            float* orow = s_out + r * OUTW;
            orow[lane] = e0 * inv;
            if (lane < C - 64) orow[64 + lane] = e1 * inv;

            // ---- branchless box decode ----
            const float cx = s_prop[r * 5 + 0];   // wave-uniform LDS -> broadcast
            const float cy = s_prop[r * 5 + 1];
            const float w  = s_prop[r * 5 + 2];
            const float h  = s_prop[r * 5 + 3];
            const float a  = s_prop[r * 5 + 4];
            const float* rg = s_reg + r * REG;
            float* drow = orow + C;

            #pragma unroll
            for (int i = 0; i < 7; ++i) {
                const int j = lane + i * 64;
                if (j < REG) {
                    const int k = j % 5;                     // magic-mul, no branch
                    float v   = rg[j];
                    float t   = v * ((k < 2) ? 0.1f : 0.2f);
                    float dim = (k & 1) ? h : w;             // k=0,2 -> w ; k=1,3 -> h
                    float lin = fmaf(t, dim, (k == 1) ? cy : cx);
                    lin = fminf(fmaxf(lin, 0.0f), 1023.0f);
                    float ex  = __expf(fminf(t, BBOX_CLIP)) * dim;
                    float ang = fmaf(v, RAD2DEG, a);
                    drow[j] = (k >= 4) ? ang : ((k >= 2) ? ex : lin);
                }
            }
        }
    }
    __syncthreads();

    // ---------------- write out (float4, fully coalesced & aligned) ----------------
    if (nrh == RPB) {
        float4* go = (float4*)(out + (size_t)row0 * OUTW);   // 15552B-mult base
        const float4* so = (const float4*)s_out;
        #pragma unroll
        for (int t = tid; t < S_OUT / 4; t += 256) go[t] = so[t];   // 972 vec4
    } else {
        for (int t = tid; t < nrh * OUTW; t += 256)
            out[(size_t)row0 * OUTW + t] = s_out[t];
    }
}

extern "C" void kernel_launch(void* const* d_in, const int* in_sizes, int n_in,
                              void* d_out, int out_size, void* d_ws, size_t ws_size,
                              hipStream_t stream) {
    const float* logits = (const float*)d_in[0];
    const float* regr   = (const float*)d_in[1];
    const float* prop   = (const float*)d_in[2];
    float* out = (float*)d_out;

    const int n_rows = in_sizes[0] / C;              // 200000
    const int blocks = (n_rows + RPB - 1) / RPB;     // 25000
    postproc_kernel<<<blocks, 256, 0, stream>>>(logits, regr, prop, out, n_rows);
}